// Round 1
// baseline (926.203 us; speedup 1.0000x reference)
//
#include <hip/hip_runtime.h>

#define KK 27
#define EPSV 1e-5f

typedef __attribute__((ext_vector_type(8))) short bf16x8;
typedef __attribute__((ext_vector_type(4))) float f32x4;

static __device__ __forceinline__ unsigned short f2bf(float f) {
    unsigned u = __float_as_uint(f);
    u = u + 0x7fffu + ((u >> 16) & 1u);
    return (unsigned short)(u >> 16);
}
static __device__ __forceinline__ float bflo(unsigned u) { return __uint_as_float(u << 16); }
static __device__ __forceinline__ float bfhi(unsigned u) { return __uint_as_float(u & 0xffff0000u); }

// --- K0: transpose+convert W1[m][k][n] (fp32) -> WT[m][n][k] (bf16) ---
__global__ void k0_wt(const float* __restrict__ W1, unsigned short* __restrict__ WT) {
    int m = blockIdx.x >> 7, n = blockIdx.x & 127, k = threadIdx.x;
    WT[((m * 128 + n) * 128) + k] = f2bf(W1[(m * 128 + k) * 128 + n]);
}

// --- K1: y = x @ W1[m] (bf16 MFMA), write y bf16 [N][128], atomic col sums/sqsums ---
__launch_bounds__(256)
__global__ void k1_gemm(const float* __restrict__ x, const unsigned short* __restrict__ WT,
                        unsigned short* __restrict__ Y, float* __restrict__ ysum,
                        float* __restrict__ ysq, int N, int m) {
    __shared__ unsigned short As[64 * 136];   // [row][k], pad 8
    __shared__ unsigned short Bs[128 * 136];  // [n][k],   pad 8
    const int t = threadIdx.x;
    const int i0 = blockIdx.x * 64;

    // stage A: 64 rows x 128 k, fp32 -> bf16
#pragma unroll
    for (int it = 0; it < 8; ++it) {
        int flat = it * 256 + t;              // 0..2047 float4-chunks
        int r = flat >> 5, c4 = (flat & 31) * 4;
        float4 v = make_float4(0.f, 0.f, 0.f, 0.f);
        if (i0 + r < N) v = *(const float4*)(x + (size_t)(i0 + r) * 128 + c4);
        ushort4 bb;
        bb.x = f2bf(v.x); bb.y = f2bf(v.y); bb.z = f2bf(v.z); bb.w = f2bf(v.w);
        *(ushort4*)(As + r * 136 + c4) = bb;
    }
    // stage B: WT[m] is [n][k] bf16, straight copy with padding
    const uint4* Wp = (const uint4*)(WT + (size_t)m * 128 * 128);
#pragma unroll
    for (int it = 0; it < 8; ++it) {
        int flat = it * 256 + t;              // 0..2047 16B-chunks
        int n = flat >> 4, kc = flat & 15;
        uint4 v = Wp[n * 16 + kc];
        *(uint4*)(Bs + n * 136 + kc * 8) = v;
    }
    __syncthreads();

    const int w = t >> 6, lane = t & 63;
    const int wr = w >> 1, wc = w & 1;
    const int r16 = lane & 15, q = lane >> 4;

    f32x4 acc[2][4];
#pragma unroll
    for (int a = 0; a < 2; ++a)
#pragma unroll
        for (int b = 0; b < 4; ++b) { acc[a][b][0] = 0.f; acc[a][b][1] = 0.f; acc[a][b][2] = 0.f; acc[a][b][3] = 0.f; }

#pragma unroll
    for (int ks = 0; ks < 4; ++ks) {
        int ko = ks * 32 + q * 8;
        bf16x8 af[2], bfr[4];
#pragma unroll
        for (int ri = 0; ri < 2; ++ri)
            af[ri] = *(const bf16x8*)(As + (wr * 32 + ri * 16 + r16) * 136 + ko);
#pragma unroll
        for (int ci = 0; ci < 4; ++ci)
            bfr[ci] = *(const bf16x8*)(Bs + (wc * 64 + ci * 16 + r16) * 136 + ko);
#pragma unroll
        for (int ri = 0; ri < 2; ++ri)
#pragma unroll
            for (int ci = 0; ci < 4; ++ci)
                acc[ri][ci] = __builtin_amdgcn_mfma_f32_16x16x32_bf16(af[ri], bfr[ci], acc[ri][ci], 0, 0, 0);
    }

    // epilogue: store bf16 y + column stats
#pragma unroll
    for (int ci = 0; ci < 4; ++ci) {
        float s = 0.f, s2 = 0.f;
        int col = wc * 64 + ci * 16 + r16;
#pragma unroll
        for (int ri = 0; ri < 2; ++ri) {
#pragma unroll
            for (int r = 0; r < 4; ++r) {
                int row = i0 + wr * 32 + ri * 16 + q * 4 + r;
                float vv = acc[ri][ci][r];
                if (row < N) {
                    Y[(size_t)row * 128 + col] = f2bf(vv);
                    s += vv; s2 += vv * vv;
                }
            }
        }
        s  += __shfl_xor(s, 16);  s  += __shfl_xor(s, 32);
        s2 += __shfl_xor(s2, 16); s2 += __shfl_xor(s2, 32);
        if (lane < 16) {
            atomicAdd(ysum + m * 128 + col, s);
            atomicAdd(ysq  + m * 128 + col, s2);
        }
    }
}

// --- K2: finalize BN1 coefficients for branch m ---
__global__ void k2_coef(const float* __restrict__ ysum, const float* __restrict__ ysq,
                        const float* __restrict__ g1, const float* __restrict__ b1,
                        float* __restrict__ a1, float* __restrict__ c1, int N, int m) {
    int c = threadIdx.x;
    float mean = ysum[m * 128 + c] / (float)N;
    float var  = ysq[m * 128 + c] / (float)N - mean * mean;
    float a = g1[m * 128 + c] * rsqrtf(var + EPSV);
    a1[m * 128 + c] = a;
    c1[m * 128 + c] = b1[m * 128 + c] - mean * a;
}

// --- K3: h = relu(y*a + c), in-place bf16 ---
__launch_bounds__(256)
__global__ void k3_apply(unsigned short* __restrict__ Y, const float* __restrict__ a1,
                         const float* __restrict__ c1, int N, int m) {
    long long flat8 = ((long long)blockIdx.x * 256 + threadIdx.x) * 8;
    if (flat8 >= (long long)N * 128) return;
    int c8 = (int)(flat8 & 127);
    uint4 yv = *(const uint4*)(Y + flat8);
    const float4 A0 = *(const float4*)(a1 + m * 128 + c8);
    const float4 A1 = *(const float4*)(a1 + m * 128 + c8 + 4);
    const float4 C0 = *(const float4*)(c1 + m * 128 + c8);
    const float4 C1 = *(const float4*)(c1 + m * 128 + c8 + 4);
    float f0 = fmaxf(0.f, bflo(yv.x) * A0.x + C0.x);
    float f1 = fmaxf(0.f, bfhi(yv.x) * A0.y + C0.y);
    float f2 = fmaxf(0.f, bflo(yv.y) * A0.z + C0.z);
    float f3 = fmaxf(0.f, bfhi(yv.y) * A0.w + C0.w);
    float f4 = fmaxf(0.f, bflo(yv.z) * A1.x + C1.x);
    float f5 = fmaxf(0.f, bfhi(yv.z) * A1.y + C1.y);
    float f6 = fmaxf(0.f, bflo(yv.w) * A1.z + C1.z);
    float f7 = fmaxf(0.f, bfhi(yv.w) * A1.w + C1.w);
    uint4 o;
    o.x = (unsigned)f2bf(f0) | ((unsigned)f2bf(f1) << 16);
    o.y = (unsigned)f2bf(f2) | ((unsigned)f2bf(f3) << 16);
    o.z = (unsigned)f2bf(f4) | ((unsigned)f2bf(f5) << 16);
    o.w = (unsigned)f2bf(f6) | ((unsigned)f2bf(f7) << 16);
    *(uint4*)(Y + flat8) = o;
}

// --- K4: gather-conv for branch m: P (+)= sum_k h[nbr[i,k]] * wk[m,k,:]
//     MODE 0: write P; MODE 1: accumulate; MODE 2: accumulate + column stats of final P
template <int MODE>
__launch_bounds__(512)
__global__ void k4_gather(const unsigned short* __restrict__ H, const int* __restrict__ nbr,
                          const float* __restrict__ wkg, float* __restrict__ P,
                          float* __restrict__ osum, float* __restrict__ osq, int N, int m) {
    __shared__ float wkL[KK * 132];
    __shared__ float ssum[128], ssq[128];
    const int t = threadIdx.x;
    for (int idx = t; idx < KK * 128; idx += 512) {
        int k = idx >> 7, c = idx & 127;
        wkL[k * 132 + c] = wkg[((m * KK) + k) * 128 + c];
    }
    if (MODE == 2) { if (t < 128) { ssum[t] = 0.f; ssq[t] = 0.f; } }
    __syncthreads();

    const int w = t >> 6, lane = t & 63;
    const int q = lane >> 4, c16 = lane & 15;
    const int wid = blockIdx.x * 8 + w;   // 0..4095
    float os[8], oq[8];
#pragma unroll
    for (int e = 0; e < 8; ++e) { os[e] = 0.f; oq[e] = 0.f; }

    for (int v = wid * 4; v < N; v += 4096 * 4) {
        int i = v + q;
        bool alive = i < N;
        float acc[8];
#pragma unroll
        for (int e = 0; e < 8; ++e) acc[e] = 0.f;
        const int base = alive ? i * KK : 0;
#pragma unroll
        for (int k = 0; k < KK; ++k) {
            int j = nbr[base + k];
            const uint4 hv = *(const uint4*)(H + (size_t)j * 128 + c16 * 8);
            const float4 wa = *(const float4*)(wkL + k * 132 + c16 * 8);
            const float4 wb = *(const float4*)(wkL + k * 132 + c16 * 8 + 4);
            acc[0] += bflo(hv.x) * wa.x; acc[1] += bfhi(hv.x) * wa.y;
            acc[2] += bflo(hv.y) * wa.z; acc[3] += bfhi(hv.y) * wa.w;
            acc[4] += bflo(hv.z) * wb.x; acc[5] += bfhi(hv.z) * wb.y;
            acc[6] += bflo(hv.w) * wb.z; acc[7] += bfhi(hv.w) * wb.w;
        }
        if (alive) {
            float* p = P + (size_t)i * 128 + c16 * 8;
            if (MODE == 0) {
                float4 v0 = {acc[0], acc[1], acc[2], acc[3]};
                float4 v1 = {acc[4], acc[5], acc[6], acc[7]};
                *(float4*)p = v0;
                *(float4*)(p + 4) = v1;
            } else {
                float4 o0 = *(const float4*)p, o1 = *(const float4*)(p + 4);
                o0.x += acc[0]; o0.y += acc[1]; o0.z += acc[2]; o0.w += acc[3];
                o1.x += acc[4]; o1.y += acc[5]; o1.z += acc[6]; o1.w += acc[7];
                *(float4*)p = o0;
                *(float4*)(p + 4) = o1;
                if (MODE == 2) {
                    os[0] += o0.x; oq[0] += o0.x * o0.x;
                    os[1] += o0.y; oq[1] += o0.y * o0.y;
                    os[2] += o0.z; oq[2] += o0.z * o0.z;
                    os[3] += o0.w; oq[3] += o0.w * o0.w;
                    os[4] += o1.x; oq[4] += o1.x * o1.x;
                    os[5] += o1.y; oq[5] += o1.y * o1.y;
                    os[6] += o1.z; oq[6] += o1.z * o1.z;
                    os[7] += o1.w; oq[7] += o1.w * o1.w;
                }
            }
        }
    }
    if (MODE == 2) {
#pragma unroll
        for (int e = 0; e < 8; ++e) {
            os[e] += __shfl_xor(os[e], 16); os[e] += __shfl_xor(os[e], 32);
            oq[e] += __shfl_xor(oq[e], 16); oq[e] += __shfl_xor(oq[e], 32);
        }
        if (lane < 16) {
#pragma unroll
            for (int e = 0; e < 8; ++e) {
                atomicAdd(ssum + c16 * 8 + e, os[e]);
                atomicAdd(ssq  + c16 * 8 + e, oq[e]);
            }
        }
        __syncthreads();
        if (t < 128) {
            atomicAdd(osum + t, ssum[t]);
            atomicAdd(osq  + t, ssq[t]);
        }
    }
}

// --- K5: finalize output BN coefficients ---
__global__ void k5_coef(const float* __restrict__ osum, const float* __restrict__ osq,
                        const float* __restrict__ g, const float* __restrict__ b,
                        float* __restrict__ ao, float* __restrict__ co, int N) {
    int c = threadIdx.x;
    float mean = osum[c] / (float)N;
    float var  = osq[c] / (float)N - mean * mean;
    float a = g[c] * rsqrtf(var + EPSV);
    ao[c] = a;
    co[c] = b[c] - mean * a;
}

// --- K6: out = relu(relu(P*a + c) + x), in-place on d_out ---
__launch_bounds__(256)
__global__ void k6_final(float* __restrict__ P, const float* __restrict__ x,
                         const float* __restrict__ ao, const float* __restrict__ co, int N) {
    long long t4 = ((long long)blockIdx.x * 256 + threadIdx.x) * 4;
    if (t4 >= (long long)N * 128) return;
    int c4 = (int)(t4 & 127);
    float4 p  = *(const float4*)(P + t4);
    float4 xv = *(const float4*)(x + t4);
    float4 a  = *(const float4*)(ao + c4);
    float4 c  = *(const float4*)(co + c4);
    float4 o;
    o.x = fmaxf(0.f, fmaxf(0.f, p.x * a.x + c.x) + xv.x);
    o.y = fmaxf(0.f, fmaxf(0.f, p.y * a.y + c.y) + xv.y);
    o.z = fmaxf(0.f, fmaxf(0.f, p.z * a.z + c.z) + xv.z);
    o.w = fmaxf(0.f, fmaxf(0.f, p.w * a.w + c.w) + xv.w);
    *(float4*)(P + t4) = o;
}

extern "C" void kernel_launch(void* const* d_in, const int* in_sizes, int n_in,
                              void* d_out, int out_size, void* d_ws, size_t ws_size,
                              hipStream_t stream) {
    const float* x     = (const float*)d_in[0];
    const int*   nbr   = (const int*)d_in[1];
    const float* W1    = (const float*)d_in[2];
    const float* g1    = (const float*)d_in[3];
    const float* b1    = (const float*)d_in[4];
    const float* wk    = (const float*)d_in[5];
    const float* g_out = (const float*)d_in[6];
    const float* b_out = (const float*)d_in[7];
    const int N = in_sizes[0] / 128;

    float* P = (float*)d_out;          // out_pre lives in d_out, finalized in-place
    char* ws = (char*)d_ws;
    float* ysum = (float*)ws;          // [512]
    float* ysq  = ysum + 512;          // [512]
    float* osum = ysq + 512;           // [128]
    float* osq  = osum + 128;          // [128]
    float* a1   = osq + 128;           // [512]
    float* c1   = a1 + 512;            // [512]
    float* ao   = c1 + 512;            // [128]
    float* co   = ao + 128;            // [128]
    unsigned short* WT = (unsigned short*)(ws + 16384);            // 4*128*128 bf16
    unsigned short* Y  = (unsigned short*)(ws + 16384 + 131072);   // N*128 bf16 (per-branch)

    // zero the atomic-accumulated stats (ws is poisoned before every timed call)
    hipMemsetAsync(d_ws, 0, 5120, stream);
    k0_wt<<<512, 128, 0, stream>>>(W1, WT);

    const int g1b = (N + 63) / 64;
    const int g3  = (int)(((long long)N * 128 / 8 + 255) / 256);
    for (int m = 0; m < 4; ++m) {
        k1_gemm<<<g1b, 256, 0, stream>>>(x, WT, Y, ysum, ysq, N, m);
        k2_coef<<<1, 128, 0, stream>>>(ysum, ysq, g1, b1, a1, c1, N, m);
        k3_apply<<<g3, 256, 0, stream>>>(Y, a1, c1, N, m);
        if (m == 0)
            k4_gather<0><<<512, 512, 0, stream>>>(Y, nbr, wk, P, osum, osq, N, m);
        else if (m == 3)
            k4_gather<2><<<512, 512, 0, stream>>>(Y, nbr, wk, P, osum, osq, N, m);
        else
            k4_gather<1><<<512, 512, 0, stream>>>(Y, nbr, wk, P, osum, osq, N, m);
    }
    k5_coef<<<1, 128, 0, stream>>>(osum, osq, g_out, b_out, ao, co, N);
    const int g6 = (int)(((long long)N * 128 / 4 + 255) / 256);
    k6_final<<<g6, 256, 0, stream>>>(P, x, ao, co, N);
}

// Round 2
// 912.169 us; speedup vs baseline: 1.0154x; 1.0154x over previous
//
#include <hip/hip_runtime.h>

#define KK 27
#define EPSV 1e-5f

typedef __attribute__((ext_vector_type(8))) short bf16x8;
typedef __attribute__((ext_vector_type(4))) float f32x4;

static __device__ __forceinline__ unsigned short f2bf(float f) {
    unsigned u = __float_as_uint(f);
    u = u + 0x7fffu + ((u >> 16) & 1u);
    return (unsigned short)(u >> 16);
}
static __device__ __forceinline__ float bflo(unsigned u) { return __uint_as_float(u << 16); }
static __device__ __forceinline__ float bfhi(unsigned u) { return __uint_as_float(u & 0xffff0000u); }

// --- K0: transpose+convert W1[m][k][n] (fp32) -> WT[m][n][k] (bf16) ---
__global__ void k0_wt(const float* __restrict__ W1, unsigned short* __restrict__ WT) {
    int m = blockIdx.x >> 7, n = blockIdx.x & 127, k = threadIdx.x;
    WT[((m * 128 + n) * 128) + k] = f2bf(W1[(m * 128 + k) * 128 + n]);
}

// --- K1: y = x @ W1[m] (bf16 MFMA), write raw y bf16 [N][128], atomic col sums/sqsums ---
__launch_bounds__(256)
__global__ void k1_gemm(const float* __restrict__ x, const unsigned short* __restrict__ WT,
                        unsigned short* __restrict__ Y, float* __restrict__ ysum,
                        float* __restrict__ ysq, int N, int m) {
    __shared__ unsigned short As[64 * 136];   // [row][k], pad 8
    __shared__ unsigned short Bs[128 * 136];  // [n][k],   pad 8
    const int t = threadIdx.x;
    const int i0 = blockIdx.x * 64;

    // stage A: 64 rows x 128 k, fp32 -> bf16
#pragma unroll
    for (int it = 0; it < 8; ++it) {
        int flat = it * 256 + t;              // 0..2047 float4-chunks
        int r = flat >> 5, c4 = (flat & 31) * 4;
        float4 v = make_float4(0.f, 0.f, 0.f, 0.f);
        if (i0 + r < N) v = *(const float4*)(x + (size_t)(i0 + r) * 128 + c4);
        ushort4 bb;
        bb.x = f2bf(v.x); bb.y = f2bf(v.y); bb.z = f2bf(v.z); bb.w = f2bf(v.w);
        *(ushort4*)(As + r * 136 + c4) = bb;
    }
    // stage B: WT[m] is [n][k] bf16, straight copy with padding
    const uint4* Wp = (const uint4*)(WT + (size_t)m * 128 * 128);
#pragma unroll
    for (int it = 0; it < 8; ++it) {
        int flat = it * 256 + t;              // 0..2047 16B-chunks
        int n = flat >> 4, kc = flat & 15;
        uint4 v = Wp[n * 16 + kc];
        *(uint4*)(Bs + n * 136 + kc * 8) = v;
    }
    __syncthreads();

    const int w = t >> 6, lane = t & 63;
    const int wr = w >> 1, wc = w & 1;
    const int r16 = lane & 15, q = lane >> 4;

    f32x4 acc[2][4];
#pragma unroll
    for (int a = 0; a < 2; ++a)
#pragma unroll
        for (int b = 0; b < 4; ++b) { acc[a][b][0] = 0.f; acc[a][b][1] = 0.f; acc[a][b][2] = 0.f; acc[a][b][3] = 0.f; }

#pragma unroll
    for (int ks = 0; ks < 4; ++ks) {
        int ko = ks * 32 + q * 8;
        bf16x8 af[2], bfr[4];
#pragma unroll
        for (int ri = 0; ri < 2; ++ri)
            af[ri] = *(const bf16x8*)(As + (wr * 32 + ri * 16 + r16) * 136 + ko);
#pragma unroll
        for (int ci = 0; ci < 4; ++ci)
            bfr[ci] = *(const bf16x8*)(Bs + (wc * 64 + ci * 16 + r16) * 136 + ko);
#pragma unroll
        for (int ri = 0; ri < 2; ++ri)
#pragma unroll
            for (int ci = 0; ci < 4; ++ci)
                acc[ri][ci] = __builtin_amdgcn_mfma_f32_16x16x32_bf16(af[ri], bfr[ci], acc[ri][ci], 0, 0, 0);
    }

    // epilogue: store bf16 y + column stats
#pragma unroll
    for (int ci = 0; ci < 4; ++ci) {
        float s = 0.f, s2 = 0.f;
        int col = wc * 64 + ci * 16 + r16;
#pragma unroll
        for (int ri = 0; ri < 2; ++ri) {
#pragma unroll
            for (int r = 0; r < 4; ++r) {
                int row = i0 + wr * 32 + ri * 16 + q * 4 + r;
                float vv = acc[ri][ci][r];
                if (row < N) {
                    Y[(size_t)row * 128 + col] = f2bf(vv);
                    s += vv; s2 += vv * vv;
                }
            }
        }
        s  += __shfl_xor(s, 16);  s  += __shfl_xor(s, 32);
        s2 += __shfl_xor(s2, 16); s2 += __shfl_xor(s2, 32);
        if (lane < 16) {
            atomicAdd(ysum + m * 128 + col, s);
            atomicAdd(ysq  + m * 128 + col, s2);
        }
    }
}

// --- K2: finalize BN1 coefficients for branch m ---
__global__ void k2_coef(const float* __restrict__ ysum, const float* __restrict__ ysq,
                        const float* __restrict__ g1, const float* __restrict__ b1,
                        float* __restrict__ a1, float* __restrict__ c1, int N, int m) {
    int c = threadIdx.x;
    float mean = ysum[m * 128 + c] / (float)N;
    float var  = ysq[m * 128 + c] / (float)N - mean * mean;
    float a = g1[m * 128 + c] * rsqrtf(var + EPSV);
    a1[m * 128 + c] = a;
    c1[m * 128 + c] = b1[m * 128 + c] - mean * a;
}

// --- K4: gather-conv for branch m, BN1+ReLU fused:
//     P (+)= sum_k relu(y[nbr[i,k]]*a + c) * wk[m,k,:]
//     MODE 0: write P; MODE 1: accumulate; MODE 2: accumulate + column stats of final P
//     Yraw: raw (pre-BN) bf16 y. a1m/c1m/wkm: pre-offset to branch m.
template <int MODE>
__launch_bounds__(256)
__global__ void k4_gather(const unsigned short* __restrict__ Yraw, const int* __restrict__ nbr,
                          const float* __restrict__ wkm, const float* __restrict__ a1m,
                          const float* __restrict__ c1m, float* __restrict__ P,
                          float* __restrict__ osum, float* __restrict__ osq, int N) {
    __shared__ float wkL[KK * 132];
    __shared__ int idxL[16 * KK];    // 16 voxels per block-sweep
    __shared__ float ssum[128], ssq[128];
    const int t = threadIdx.x;
    for (int idx = t; idx < KK * 128; idx += 256) {
        int k = idx >> 7, c = idx & 127;
        wkL[k * 132 + c] = wkm[k * 128 + c];
    }
    if (MODE == 2) { if (t < 128) { ssum[t] = 0.f; ssq[t] = 0.f; } }

    const int w = t >> 6, lane = t & 63;
    const int q = lane >> 4, c16 = lane & 15;
    const int slot = w * 4 + q;              // 0..15: which voxel of the block-sweep

    // BN coefficients for this lane's 8 channels
    float aR[8], cR[8];
    {
        const float4 A0 = *(const float4*)(a1m + c16 * 8);
        const float4 A1 = *(const float4*)(a1m + c16 * 8 + 4);
        const float4 C0 = *(const float4*)(c1m + c16 * 8);
        const float4 C1 = *(const float4*)(c1m + c16 * 8 + 4);
        aR[0]=A0.x; aR[1]=A0.y; aR[2]=A0.z; aR[3]=A0.w;
        aR[4]=A1.x; aR[5]=A1.y; aR[6]=A1.z; aR[7]=A1.w;
        cR[0]=C0.x; cR[1]=C0.y; cR[2]=C0.z; cR[3]=C0.w;
        cR[4]=C1.x; cR[5]=C1.y; cR[6]=C1.z; cR[7]=C1.w;
    }

    float os[8], oq[8];
#pragma unroll
    for (int e = 0; e < 8; ++e) { os[e] = 0.f; oq[e] = 0.f; }

    const int sweep = gridDim.x * 16;
    const int NK = N * KK;
    for (int base = blockIdx.x * 16; base < N; base += sweep) {
        __syncthreads();   // wkL visible (iter 0); idxL reuse safe (iter >0)
        // cooperative stage of 16*27 neighbor indices
        for (int s = t; s < 16 * KK; s += 256) {
            int flat = base * KK + s;
            idxL[s] = (flat < NK) ? nbr[flat] : 0;
        }
        __syncthreads();

        const int vox = base + slot;
        const bool alive = vox < N;
        const int* ip = idxL + slot * KK;
        float acc[8];
#pragma unroll
        for (int e = 0; e < 8; ++e) acc[e] = 0.f;

#pragma unroll
        for (int k = 0; k < KK; ++k) {
            int j = ip[k];
            const uint4 hv = *(const uint4*)(Yraw + (size_t)j * 128 + c16 * 8);
            const float4 wa = *(const float4*)(wkL + k * 132 + c16 * 8);
            const float4 wb = *(const float4*)(wkL + k * 132 + c16 * 8 + 4);
            float h0 = fmaxf(0.f, bflo(hv.x) * aR[0] + cR[0]);
            float h1 = fmaxf(0.f, bfhi(hv.x) * aR[1] + cR[1]);
            float h2 = fmaxf(0.f, bflo(hv.y) * aR[2] + cR[2]);
            float h3 = fmaxf(0.f, bfhi(hv.y) * aR[3] + cR[3]);
            float h4 = fmaxf(0.f, bflo(hv.z) * aR[4] + cR[4]);
            float h5 = fmaxf(0.f, bfhi(hv.z) * aR[5] + cR[5]);
            float h6 = fmaxf(0.f, bflo(hv.w) * aR[6] + cR[6]);
            float h7 = fmaxf(0.f, bfhi(hv.w) * aR[7] + cR[7]);
            acc[0] += h0 * wa.x; acc[1] += h1 * wa.y;
            acc[2] += h2 * wa.z; acc[3] += h3 * wa.w;
            acc[4] += h4 * wb.x; acc[5] += h5 * wb.y;
            acc[6] += h6 * wb.z; acc[7] += h7 * wb.w;
        }

        if (alive) {
            float* p = P + (size_t)vox * 128 + c16 * 8;
            if (MODE == 0) {
                float4 v0 = {acc[0], acc[1], acc[2], acc[3]};
                float4 v1 = {acc[4], acc[5], acc[6], acc[7]};
                *(float4*)p = v0;
                *(float4*)(p + 4) = v1;
            } else {
                float4 o0 = *(const float4*)p, o1 = *(const float4*)(p + 4);
                o0.x += acc[0]; o0.y += acc[1]; o0.z += acc[2]; o0.w += acc[3];
                o1.x += acc[4]; o1.y += acc[5]; o1.z += acc[6]; o1.w += acc[7];
                *(float4*)p = o0;
                *(float4*)(p + 4) = o1;
                if (MODE == 2) {
                    os[0] += o0.x; oq[0] += o0.x * o0.x;
                    os[1] += o0.y; oq[1] += o0.y * o0.y;
                    os[2] += o0.z; oq[2] += o0.z * o0.z;
                    os[3] += o0.w; oq[3] += o0.w * o0.w;
                    os[4] += o1.x; oq[4] += o1.x * o1.x;
                    os[5] += o1.y; oq[5] += o1.y * o1.y;
                    os[6] += o1.z; oq[6] += o1.z * o1.z;
                    os[7] += o1.w; oq[7] += o1.w * o1.w;
                }
            }
        }
    }
    if (MODE == 2) {
#pragma unroll
        for (int e = 0; e < 8; ++e) {
            os[e] += __shfl_xor(os[e], 16); os[e] += __shfl_xor(os[e], 32);
            oq[e] += __shfl_xor(oq[e], 16); oq[e] += __shfl_xor(oq[e], 32);
        }
        __syncthreads();
        if (lane < 16) {
#pragma unroll
            for (int e = 0; e < 8; ++e) {
                atomicAdd(ssum + c16 * 8 + e, os[e]);
                atomicAdd(ssq  + c16 * 8 + e, oq[e]);
            }
        }
        __syncthreads();
        if (t < 128) {
            atomicAdd(osum + t, ssum[t]);
            atomicAdd(osq  + t, ssq[t]);
        }
    }
}

// --- K5: finalize output BN coefficients ---
__global__ void k5_coef(const float* __restrict__ osum, const float* __restrict__ osq,
                        const float* __restrict__ g, const float* __restrict__ b,
                        float* __restrict__ ao, float* __restrict__ co, int N) {
    int c = threadIdx.x;
    float mean = osum[c] / (float)N;
    float var  = osq[c] / (float)N - mean * mean;
    float a = g[c] * rsqrtf(var + EPSV);
    ao[c] = a;
    co[c] = b[c] - mean * a;
}

// --- K6: out = relu(relu(P*a + c) + x), in-place on d_out ---
__launch_bounds__(256)
__global__ void k6_final(float* __restrict__ P, const float* __restrict__ x,
                         const float* __restrict__ ao, const float* __restrict__ co, int N) {
    long long t4 = ((long long)blockIdx.x * 256 + threadIdx.x) * 4;
    if (t4 >= (long long)N * 128) return;
    int c4 = (int)(t4 & 127);
    float4 p  = *(const float4*)(P + t4);
    float4 xv = *(const float4*)(x + t4);
    float4 a  = *(const float4*)(ao + c4);
    float4 c  = *(const float4*)(co + c4);
    float4 o;
    o.x = fmaxf(0.f, fmaxf(0.f, p.x * a.x + c.x) + xv.x);
    o.y = fmaxf(0.f, fmaxf(0.f, p.y * a.y + c.y) + xv.y);
    o.z = fmaxf(0.f, fmaxf(0.f, p.z * a.z + c.z) + xv.z);
    o.w = fmaxf(0.f, fmaxf(0.f, p.w * a.w + c.w) + xv.w);
    *(float4*)(P + t4) = o;
}

extern "C" void kernel_launch(void* const* d_in, const int* in_sizes, int n_in,
                              void* d_out, int out_size, void* d_ws, size_t ws_size,
                              hipStream_t stream) {
    const float* x     = (const float*)d_in[0];
    const int*   nbr   = (const int*)d_in[1];
    const float* W1    = (const float*)d_in[2];
    const float* g1    = (const float*)d_in[3];
    const float* b1    = (const float*)d_in[4];
    const float* wk    = (const float*)d_in[5];
    const float* g_out = (const float*)d_in[6];
    const float* b_out = (const float*)d_in[7];
    const int N = in_sizes[0] / 128;

    float* P = (float*)d_out;          // out_pre lives in d_out, finalized in-place
    char* ws = (char*)d_ws;
    float* ysum = (float*)ws;          // [512]
    float* ysq  = ysum + 512;          // [512]
    float* osum = ysq + 512;           // [128]
    float* osq  = osum + 128;          // [128]
    float* a1   = osq + 128;           // [512]
    float* c1   = a1 + 512;            // [512]
    float* ao   = c1 + 512;            // [128]
    float* co   = ao + 128;            // [128]
    unsigned short* WT = (unsigned short*)(ws + 16384);            // 4*128*128 bf16
    unsigned short* Y  = (unsigned short*)(ws + 16384 + 131072);   // N*128 bf16 (per-branch)

    // zero the atomic-accumulated stats (ws is poisoned before every timed call)
    hipMemsetAsync(d_ws, 0, 5120, stream);
    k0_wt<<<512, 128, 0, stream>>>(W1, WT);

    const int g1b = (N + 63) / 64;
    for (int m = 0; m < 4; ++m) {
        k1_gemm<<<g1b, 256, 0, stream>>>(x, WT, Y, ysum, ysq, N, m);
        k2_coef<<<1, 128, 0, stream>>>(ysum, ysq, g1, b1, a1, c1, N, m);
        if (m == 0)
            k4_gather<0><<<2048, 256, 0, stream>>>(Y, nbr, wk + m * KK * 128, a1 + m * 128,
                                                   c1 + m * 128, P, osum, osq, N);
        else if (m == 3)
            k4_gather<2><<<2048, 256, 0, stream>>>(Y, nbr, wk + m * KK * 128, a1 + m * 128,
                                                   c1 + m * 128, P, osum, osq, N);
        else
            k4_gather<1><<<2048, 256, 0, stream>>>(Y, nbr, wk + m * KK * 128, a1 + m * 128,
                                                   c1 + m * 128, P, osum, osq, N);
    }
    k5_coef<<<1, 128, 0, stream>>>(osum, osq, g_out, b_out, ao, co, N);
    const int g6 = (int)(((long long)N * 128 / 4 + 255) / 256);
    k6_final<<<g6, 256, 0, stream>>>(P, x, ao, co, N);
}

// Round 3
// 743.524 us; speedup vs baseline: 1.2457x; 1.2268x over previous
//
#include <hip/hip_runtime.h>

#define KK 27
#define EPSV 1e-5f

typedef __attribute__((ext_vector_type(8))) short bf16x8;
typedef __attribute__((ext_vector_type(4))) float f32x4;

static __device__ __forceinline__ unsigned short f2bf(float f) {
    unsigned u = __float_as_uint(f);
    u = u + 0x7fffu + ((u >> 16) & 1u);
    return (unsigned short)(u >> 16);
}
static __device__ __forceinline__ float bflo(unsigned u) { return __uint_as_float(u << 16); }
static __device__ __forceinline__ float bfhi(unsigned u) { return __uint_as_float(u & 0xffff0000u); }

// --- K0: transpose+convert W1[m][k][n] (fp32) -> WT[m][n][k] (bf16) ---
__global__ void k0_wt(const float* __restrict__ W1, unsigned short* __restrict__ WT) {
    int m = blockIdx.x >> 7, n = blockIdx.x & 127, k = threadIdx.x;
    WT[((m * 128 + n) * 128) + k] = f2bf(W1[(m * 128 + k) * 128 + n]);
}

// --- KA: y_m = x @ W1[m] for m in [m0,m1); Yall[row][ (m-m0)*128 + c ] bf16 (row stride ystride)
//     x staged once; acc bounced through LDS for coalesced uint4 stores; col stats via shfl+atomics.
__launch_bounds__(256)
__global__ void kA_gemm(const float* __restrict__ x, const unsigned short* __restrict__ WT,
                        unsigned short* __restrict__ Yall, float* __restrict__ ysum,
                        float* __restrict__ ysq, int N, int m0, int m1, int ystride) {
    __shared__ unsigned short As[64 * 136];   // [row][k], pad 8
    __shared__ unsigned short Bs[128 * 136];  // [n][k], pad 8; reused as Ys tile per m
    const int t = threadIdx.x;
    const int i0 = blockIdx.x * 64;

    // stage A: 64 rows x 128 k, fp32 -> bf16 (once)
#pragma unroll
    for (int it = 0; it < 8; ++it) {
        int flat = it * 256 + t;              // float4-chunks
        int r = flat >> 5, c4 = (flat & 31) * 4;
        float4 v = make_float4(0.f, 0.f, 0.f, 0.f);
        if (i0 + r < N) v = *(const float4*)(x + (size_t)(i0 + r) * 128 + c4);
        ushort4 bb;
        bb.x = f2bf(v.x); bb.y = f2bf(v.y); bb.z = f2bf(v.z); bb.w = f2bf(v.w);
        *(ushort4*)(As + r * 136 + c4) = bb;
    }

    const int w = t >> 6, lane = t & 63;
    const int wr = w >> 1, wc = w & 1;
    const int r16 = lane & 15, q = lane >> 4;

    for (int m = m0; m < m1; ++m) {
        __syncthreads();   // prior m's coop-store (reads Bs space) complete
        const uint4* Wp = (const uint4*)(WT + (size_t)m * 128 * 128);
#pragma unroll
        for (int it = 0; it < 8; ++it) {
            int flat = it * 256 + t;          // 16B-chunks
            int n = flat >> 4, kc = flat & 15;
            uint4 v = Wp[n * 16 + kc];
            *(uint4*)(Bs + n * 136 + kc * 8) = v;
        }
        __syncthreads();

        f32x4 acc[2][4];
#pragma unroll
        for (int a = 0; a < 2; ++a)
#pragma unroll
            for (int b = 0; b < 4; ++b) { acc[a][b][0] = 0.f; acc[a][b][1] = 0.f; acc[a][b][2] = 0.f; acc[a][b][3] = 0.f; }

#pragma unroll
        for (int ks = 0; ks < 4; ++ks) {
            int ko = ks * 32 + q * 8;
            bf16x8 af[2], bfr[4];
#pragma unroll
            for (int ri = 0; ri < 2; ++ri)
                af[ri] = *(const bf16x8*)(As + (wr * 32 + ri * 16 + r16) * 136 + ko);
#pragma unroll
            for (int ci = 0; ci < 4; ++ci)
                bfr[ci] = *(const bf16x8*)(Bs + (wc * 64 + ci * 16 + r16) * 136 + ko);
#pragma unroll
            for (int ri = 0; ri < 2; ++ri)
#pragma unroll
                for (int ci = 0; ci < 4; ++ci)
                    acc[ri][ci] = __builtin_amdgcn_mfma_f32_16x16x32_bf16(af[ri], bfr[ci], acc[ri][ci], 0, 0, 0);
        }

        // column stats (N-guarded) via shfl + one atomic per (col, stat)
#pragma unroll
        for (int ci = 0; ci < 4; ++ci) {
            float s = 0.f, s2 = 0.f;
#pragma unroll
            for (int ri = 0; ri < 2; ++ri) {
#pragma unroll
                for (int r = 0; r < 4; ++r) {
                    int row = i0 + wr * 32 + ri * 16 + q * 4 + r;
                    float vv = acc[ri][ci][r];
                    if (row < N) { s += vv; s2 += vv * vv; }
                }
            }
            s  += __shfl_xor(s, 16);  s  += __shfl_xor(s, 32);
            s2 += __shfl_xor(s2, 16); s2 += __shfl_xor(s2, 32);
            if (lane < 16) {
                int col = wc * 64 + ci * 16 + r16;
                atomicAdd(ysum + m * 128 + col, s);
                atomicAdd(ysq  + m * 128 + col, s2);
            }
        }

        __syncthreads();   // all waves done reading Bs for MFMA
        // bounce acc -> Bs space (row-major bf16 tile [64][136])
        unsigned short* Ys = Bs;
#pragma unroll
        for (int ci = 0; ci < 4; ++ci) {
            int col = wc * 64 + ci * 16 + r16;
#pragma unroll
            for (int ri = 0; ri < 2; ++ri) {
#pragma unroll
                for (int r = 0; r < 4; ++r) {
                    int rl = wr * 32 + ri * 16 + q * 4 + r;
                    Ys[rl * 136 + col] = f2bf(acc[ri][ci][r]);
                }
            }
        }
        __syncthreads();
        // coalesced store: 64 rows x 128 cols bf16 = 1024 uint4 chunks
        const int cb = (m - m0) * 128;
#pragma unroll
        for (int it = 0; it < 4; ++it) {
            int chunk = it * 256 + t;
            int row = chunk >> 4, c8 = (chunk & 15) * 8;
            if (i0 + row < N)
                *(uint4*)(Yall + (size_t)(i0 + row) * ystride + cb + c8) = *(const uint4*)(Ys + row * 136 + c8);
        }
    }
}

// --- K2: finalize BN1 coefficients for branches [m0, m0+nm) ---
__global__ void k2_coef(const float* __restrict__ ysum, const float* __restrict__ ysq,
                        const float* __restrict__ g1, const float* __restrict__ b1,
                        float* __restrict__ a1, float* __restrict__ c1, int N, int m0) {
    int c = threadIdx.x & 127;
    int m = m0 + (threadIdx.x >> 7);
    float mean = ysum[m * 128 + c] / (float)N;
    float var  = ysq[m * 128 + c] / (float)N - mean * mean;
    float a = g1[m * 128 + c] * rsqrtf(var + EPSV);
    a1[m * 128 + c] = a;
    c1[m * 128 + c] = b1[m * 128 + c] - mean * a;
}

// --- K4: gather-conv for branch m with fused BN1+ReLU:
//     P (+)= sum_k relu(y[nbr[i,k]]*a + c) * wk[m,k,:]
//     Ym: bf16 y base pre-offset to branch m's column slice; row stride ystride (elems).
//     No in-loop barriers; each block = 16 voxels, grid covers N.
template <int MODE>
__launch_bounds__(256)
__global__ void k4_gather(const unsigned short* __restrict__ Ym, int ystride,
                          const int* __restrict__ nbr,
                          const float* __restrict__ wkm, const float* __restrict__ a1m,
                          const float* __restrict__ c1m, float* __restrict__ P,
                          float* __restrict__ osum, float* __restrict__ osq, int N) {
    __shared__ float wkL[KK * 132];
    __shared__ float ssum[128], ssq[128];
    const int t = threadIdx.x;
    for (int idx = t; idx < KK * 128; idx += 256) {
        int k = idx >> 7, c = idx & 127;
        wkL[k * 132 + c] = wkm[k * 128 + c];
    }
    if (MODE == 2) { if (t < 128) { ssum[t] = 0.f; ssq[t] = 0.f; } }

    const int w = t >> 6, lane = t & 63;
    const int q = lane >> 4, c16 = lane & 15;
    const int slot = w * 4 + q;              // 0..15
    const int vox = blockIdx.x * 16 + slot;
    const bool alive = vox < N;

    // BN coefficients for this lane's 8 channels
    float aR[8], cR[8];
    {
        const float4 A0 = *(const float4*)(a1m + c16 * 8);
        const float4 A1 = *(const float4*)(a1m + c16 * 8 + 4);
        const float4 C0 = *(const float4*)(c1m + c16 * 8);
        const float4 C1 = *(const float4*)(c1m + c16 * 8 + 4);
        aR[0]=A0.x; aR[1]=A0.y; aR[2]=A0.z; aR[3]=A0.w;
        aR[4]=A1.x; aR[5]=A1.y; aR[6]=A1.z; aR[7]=A1.w;
        cR[0]=C0.x; cR[1]=C0.y; cR[2]=C0.z; cR[3]=C0.w;
        cR[4]=C1.x; cR[5]=C1.y; cR[6]=C1.z; cR[7]=C1.w;
    }
    __syncthreads();   // wkL (and ssum init) visible

    const long long base = alive ? (long long)vox * KK : 0;
    float acc[8];
#pragma unroll
    for (int e = 0; e < 8; ++e) acc[e] = 0.f;

#pragma unroll
    for (int k = 0; k < KK; ++k) {
        int j = nbr[base + k];                 // quad lanes share address (broadcast)
        const uint4 hv = *(const uint4*)(Ym + (size_t)j * ystride + c16 * 8);
        const float4 wa = *(const float4*)(wkL + k * 132 + c16 * 8);
        const float4 wb = *(const float4*)(wkL + k * 132 + c16 * 8 + 4);
        float h0 = fmaxf(0.f, bflo(hv.x) * aR[0] + cR[0]);
        float h1 = fmaxf(0.f, bfhi(hv.x) * aR[1] + cR[1]);
        float h2 = fmaxf(0.f, bflo(hv.y) * aR[2] + cR[2]);
        float h3 = fmaxf(0.f, bfhi(hv.y) * aR[3] + cR[3]);
        float h4 = fmaxf(0.f, bflo(hv.z) * aR[4] + cR[4]);
        float h5 = fmaxf(0.f, bfhi(hv.z) * aR[5] + cR[5]);
        float h6 = fmaxf(0.f, bflo(hv.w) * aR[6] + cR[6]);
        float h7 = fmaxf(0.f, bfhi(hv.w) * aR[7] + cR[7]);
        acc[0] += h0 * wa.x; acc[1] += h1 * wa.y;
        acc[2] += h2 * wa.z; acc[3] += h3 * wa.w;
        acc[4] += h4 * wb.x; acc[5] += h5 * wb.y;
        acc[6] += h6 * wb.z; acc[7] += h7 * wb.w;
    }

    float os[8], oq[8];
    if (alive) {
        float* p = P + (size_t)vox * 128 + c16 * 8;
        if (MODE == 0) {
            float4 v0 = {acc[0], acc[1], acc[2], acc[3]};
            float4 v1 = {acc[4], acc[5], acc[6], acc[7]};
            *(float4*)p = v0;
            *(float4*)(p + 4) = v1;
        } else {
            float4 o0 = *(const float4*)p, o1 = *(const float4*)(p + 4);
            o0.x += acc[0]; o0.y += acc[1]; o0.z += acc[2]; o0.w += acc[3];
            o1.x += acc[4]; o1.y += acc[5]; o1.z += acc[6]; o1.w += acc[7];
            *(float4*)p = o0;
            *(float4*)(p + 4) = o1;
            if (MODE == 2) {
                os[0] = o0.x; oq[0] = o0.x * o0.x;
                os[1] = o0.y; oq[1] = o0.y * o0.y;
                os[2] = o0.z; oq[2] = o0.z * o0.z;
                os[3] = o0.w; oq[3] = o0.w * o0.w;
                os[4] = o1.x; oq[4] = o1.x * o1.x;
                os[5] = o1.y; oq[5] = o1.y * o1.y;
                os[6] = o1.z; oq[6] = o1.z * o1.z;
                os[7] = o1.w; oq[7] = o1.w * o1.w;
            }
        }
    }
    if (MODE == 2) {
        if (!alive) {
#pragma unroll
            for (int e = 0; e < 8; ++e) { os[e] = 0.f; oq[e] = 0.f; }
        }
#pragma unroll
        for (int e = 0; e < 8; ++e) {
            os[e] += __shfl_xor(os[e], 16); os[e] += __shfl_xor(os[e], 32);
            oq[e] += __shfl_xor(oq[e], 16); oq[e] += __shfl_xor(oq[e], 32);
        }
        if (lane < 16) {
#pragma unroll
            for (int e = 0; e < 8; ++e) {
                atomicAdd(ssum + c16 * 8 + e, os[e]);
                atomicAdd(ssq  + c16 * 8 + e, oq[e]);
            }
        }
        __syncthreads();
        if (t < 128) {
            atomicAdd(osum + t, ssum[t]);
            atomicAdd(osq  + t, ssq[t]);
        }
    }
}

// --- K5: finalize output BN coefficients ---
__global__ void k5_coef(const float* __restrict__ osum, const float* __restrict__ osq,
                        const float* __restrict__ g, const float* __restrict__ b,
                        float* __restrict__ ao, float* __restrict__ co, int N) {
    int c = threadIdx.x;
    float mean = osum[c] / (float)N;
    float var  = osq[c] / (float)N - mean * mean;
    float a = g[c] * rsqrtf(var + EPSV);
    ao[c] = a;
    co[c] = b[c] - mean * a;
}

// --- K6: out = relu(relu(P*a + c) + x), in-place on d_out ---
__launch_bounds__(256)
__global__ void k6_final(float* __restrict__ P, const float* __restrict__ x,
                         const float* __restrict__ ao, const float* __restrict__ co, int N) {
    long long t4 = ((long long)blockIdx.x * 256 + threadIdx.x) * 4;
    if (t4 >= (long long)N * 128) return;
    int c4 = (int)(t4 & 127);
    float4 p  = *(const float4*)(P + t4);
    float4 xv = *(const float4*)(x + t4);
    float4 a  = *(const float4*)(ao + c4);
    float4 c  = *(const float4*)(co + c4);
    float4 o;
    o.x = fmaxf(0.f, fmaxf(0.f, p.x * a.x + c.x) + xv.x);
    o.y = fmaxf(0.f, fmaxf(0.f, p.y * a.y + c.y) + xv.y);
    o.z = fmaxf(0.f, fmaxf(0.f, p.z * a.z + c.z) + xv.z);
    o.w = fmaxf(0.f, fmaxf(0.f, p.w * a.w + c.w) + xv.w);
    *(float4*)(P + t4) = o;
}

extern "C" void kernel_launch(void* const* d_in, const int* in_sizes, int n_in,
                              void* d_out, int out_size, void* d_ws, size_t ws_size,
                              hipStream_t stream) {
    const float* x     = (const float*)d_in[0];
    const int*   nbr   = (const int*)d_in[1];
    const float* W1    = (const float*)d_in[2];
    const float* g1    = (const float*)d_in[3];
    const float* b1    = (const float*)d_in[4];
    const float* wk    = (const float*)d_in[5];
    const float* g_out = (const float*)d_in[6];
    const float* b_out = (const float*)d_in[7];
    const int N = in_sizes[0] / 128;

    float* P = (float*)d_out;
    char* ws = (char*)d_ws;
    float* ysum = (float*)ws;          // [512]
    float* ysq  = ysum + 512;          // [512]
    float* osum = ysq + 512;           // [128]
    float* osq  = osum + 128;          // [128]
    float* a1   = osq + 128;           // [512]
    float* c1   = a1 + 512;            // [512]
    float* ao   = c1 + 512;            // [128]
    float* co   = ao + 128;            // [128]
    unsigned short* WT = (unsigned short*)(ws + 16384);            // 4*128*128 bf16
    unsigned short* Y  = (unsigned short*)(ws + 16384 + 131072);   // Y buffer

    const bool fused = ws_size >= (size_t)16384 + 131072 + (size_t)N * 512 * 2;

    hipMemsetAsync(d_ws, 0, 5120, stream);
    k0_wt<<<512, 128, 0, stream>>>(W1, WT);

    const int gA = (N + 63) / 64;
    const int g4 = (N + 15) / 16;

    if (fused) {
        kA_gemm<<<gA, 256, 0, stream>>>(x, WT, Y, ysum, ysq, N, 0, 4, 512);
        k2_coef<<<1, 512, 0, stream>>>(ysum, ysq, g1, b1, a1, c1, N, 0);
        for (int m = 0; m < 4; ++m) {
            const unsigned short* Ym = Y + m * 128;
            if (m == 0)
                k4_gather<0><<<g4, 256, 0, stream>>>(Ym, 512, nbr, wk + m * KK * 128,
                                                     a1 + m * 128, c1 + m * 128, P, osum, osq, N);
            else if (m == 3)
                k4_gather<2><<<g4, 256, 0, stream>>>(Ym, 512, nbr, wk + m * KK * 128,
                                                     a1 + m * 128, c1 + m * 128, P, osum, osq, N);
            else
                k4_gather<1><<<g4, 256, 0, stream>>>(Ym, 512, nbr, wk + m * KK * 128,
                                                     a1 + m * 128, c1 + m * 128, P, osum, osq, N);
        }
    } else {
        for (int m = 0; m < 4; ++m) {
            kA_gemm<<<gA, 256, 0, stream>>>(x, WT, Y, ysum, ysq, N, m, m + 1, 128);
            k2_coef<<<1, 128, 0, stream>>>(ysum, ysq, g1, b1, a1, c1, N, m);
            if (m == 0)
                k4_gather<0><<<g4, 256, 0, stream>>>(Y, 128, nbr, wk + m * KK * 128,
                                                     a1 + m * 128, c1 + m * 128, P, osum, osq, N);
            else if (m == 3)
                k4_gather<2><<<g4, 256, 0, stream>>>(Y, 128, nbr, wk + m * KK * 128,
                                                     a1 + m * 128, c1 + m * 128, P, osum, osq, N);
            else
                k4_gather<1><<<g4, 256, 0, stream>>>(Y, 128, nbr, wk + m * KK * 128,
                                                     a1 + m * 128, c1 + m * 128, P, osum, osq, N);
        }
    }
    k5_coef<<<1, 128, 0, stream>>>(osum, osq, g_out, b_out, ao, co, N);
    const int g6 = (int)(((long long)N * 128 / 4 + 255) / 256);
    k6_final<<<g6, 256, 0, stream>>>(P, x, ao, co, N);
}